// Round 17
// baseline (1572.791 us; speedup 1.0000x reference)
//
#include <hip/hip_runtime.h>
#include <hip/hip_bf16.h>

// LBEBM R17: langevin = R11/R15 verbatim (0.96ms, 56 VGPR, no spill).
// Decoder re-tiled to 16 samples/wg (LDS 114KB->61KB -> 2 wg/CU).
// copy_ftraj folded into fused_prep (one launch fewer).

#define NTOT 65536

typedef __attribute__((ext_vector_type(8))) _Float16 f16x8;
typedef __attribute__((ext_vector_type(8))) short bf16x8;
typedef __attribute__((ext_vector_type(4))) float f32x4;
typedef __attribute__((ext_vector_type(4))) unsigned short u16x4;

__device__ __forceinline__ unsigned short f2bf(float f) {
    union { float f; unsigned int u; } v; v.f = f;
    unsigned int r = v.u + 0x7fffu + ((v.u >> 16) & 1u);
    return (unsigned short)(r >> 16);
}
__device__ __forceinline__ float bf2f(unsigned short h) {
    union { unsigned int u; float f; } v; v.u = ((unsigned int)h) << 16;
    return v.f;
}
__device__ __forceinline__ unsigned short f2h(float f) {
    union { _Float16 h; unsigned short u; } v; v.h = (_Float16)f; return v.u;
}
__device__ __forceinline__ float h2f(unsigned short u) {
    union { unsigned short u; _Float16 h; } v; v.u = u; return (float)v.h;
}
// gelu val+grad, fast erf (A&S 7.1.26, |err|<=1.5e-7, shares exp(-x^2/2))
__device__ __forceinline__ void gelu_pair_fast(float x, float& val, float& grad) {
    float e = __expf(-0.5f * x * x);
    float pdf = 0.3989422804014326779f * e;
    float y = fabsf(x) * 0.70710678118654752440f;
    float t = __builtin_amdgcn_rcpf(fmaf(0.3275911f, y, 1.0f));
    float poly = t * (0.254829592f + t * (-0.284496736f + t * (1.421413741f
               + t * (-1.453152027f + t * 1.061405429f))));
    float erfv = copysignf(fmaf(-poly, e, 1.0f), x);
    float cdf = fmaf(0.5f, erfv, 0.5f);
    val = x * cdf;
    grad = fmaf(x, pdf, cdf);
}

// ---- fused weight prep + ftraj passthrough: one launch, 11 segments ----
__device__ __forceinline__ void pack_w_elem(const float* src, unsigned short* dst,
                                            int srcR, int srcC, int transposed,
                                            int KT, int idx) {
    int e = idx & 7, lane = (idx >> 3) & 63, t = idx >> 9;
    int kt = t % KT, nt = t / KT;
    int n = nt * 16 + (lane & 15);
    int k = kt * 32 + (lane >> 4) * 8 + e;
    float v = 0.f;
    if (transposed) { if (k < srcR && n < srcC) v = src[(size_t)k * srcC + n]; }
    else            { if (n < srcR && k < srcC) v = src[(size_t)n * srcC + k]; }
    dst[idx] = f2h(v);
}
__device__ __forceinline__ void prep_wT_elem(const float* src, unsigned short* dst,
                                             int K, int Kp, int Nsrc, int idx) {
    int n = idx / Kp, k = idx - n * Kp;
    float v = (k < K && n < Nsrc) ? src[(size_t)k * Nsrc + n] : 0.f;
    dst[idx] = f2bf(v);
}

#define SZ_W1T  6656      // 13*1*512
#define SZ_W2T  46592     // 13*7*512
#define SZ_W2D  46592
#define SZ_W3T  7168      // 2*7*512
#define SZ_W3D  6656
#define SZ_W1D  3584      // 1*7*512
#define SZ_T1   40960     // 1024*40
#define SZ_T2   528384    // 512*1032
#define SZ_T3   532480    // 1024*520
#define SZ_T4   16512     // 16*1032
#define SZ_CP   262144    // NTOT*16/4 float4 copies
#define SZ_ALL  (SZ_W1T+SZ_W2T+SZ_W2D+SZ_W3T+SZ_W3D+SZ_W1D+SZ_T1+SZ_T2+SZ_T3+SZ_T4+SZ_CP)

__global__ void fused_prep_kernel(
    const float* __restrict__ ew1, const float* __restrict__ ew2,
    const float* __restrict__ ew3,
    const float* __restrict__ dw1, const float* __restrict__ dw2,
    const float* __restrict__ dw3, const float* __restrict__ dw4,
    unsigned short* __restrict__ w1tp, unsigned short* __restrict__ w2tp,
    unsigned short* __restrict__ w2dp, unsigned short* __restrict__ w3tp,
    unsigned short* __restrict__ w3dp, unsigned short* __restrict__ w1dp,
    unsigned short* __restrict__ wsT1, unsigned short* __restrict__ wsT2,
    unsigned short* __restrict__ wsT3, unsigned short* __restrict__ wsT4,
    const float4* __restrict__ cpsrc, float4* __restrict__ cpdst)
{
    int idx = blockIdx.x * blockDim.x + threadIdx.x;
    if (idx < SZ_W1T) { pack_w_elem(ew1, w1tp, 32, 200, 1, 1, idx); return; }
    idx -= SZ_W1T;
    if (idx < SZ_W2T) { pack_w_elem(ew2, w2tp, 200, 200, 1, 7, idx); return; }
    idx -= SZ_W2T;
    if (idx < SZ_W2D) { pack_w_elem(ew2, w2dp, 200, 200, 0, 7, idx); return; }
    idx -= SZ_W2D;
    if (idx < SZ_W3T) { pack_w_elem(ew3, w3tp, 200, 20, 1, 7, idx); return; }
    idx -= SZ_W3T;
    if (idx < SZ_W3D) { pack_w_elem(ew3, w3dp, 200, 20, 0, 1, idx); return; }
    idx -= SZ_W3D;
    if (idx < SZ_W1D) { pack_w_elem(ew1, w1dp, 32, 200, 0, 7, idx); return; }
    idx -= SZ_W1D;
    if (idx < SZ_T1) { prep_wT_elem(dw1, wsT1, 32, 40, 1024, idx); return; }
    idx -= SZ_T1;
    if (idx < SZ_T2) { prep_wT_elem(dw2, wsT2, 1024, 1032, 512, idx); return; }
    idx -= SZ_T2;
    if (idx < SZ_T3) { prep_wT_elem(dw3, wsT3, 512, 520, 1024, idx); return; }
    idx -= SZ_T3;
    if (idx < SZ_T4) { prep_wT_elem(dw4, wsT4, 1024, 1032, 10, idx); return; }
    idx -= SZ_T4;
    if (idx < SZ_CP) { cpdst[idx] = cpsrc[idx]; }
}

// ---------------- Langevin: 32 samples/wg, 512 threads, ~75KB LDS, 2 wg/CU --------
__global__ __launch_bounds__(512, 4) void langevin_kernel(
    const float* __restrict__ ftraj, const float* __restrict__ z0,
    const float* __restrict__ noise,
    const unsigned short* __restrict__ w1tp, const unsigned short* __restrict__ w2tp,
    const unsigned short* __restrict__ w2dp, const unsigned short* __restrict__ w3tp,
    const unsigned short* __restrict__ w3dp, const unsigned short* __restrict__ w1dp,
    const float* __restrict__ b1, const float* __restrict__ b2,
    const float* __restrict__ b3, float* __restrict__ zout)
{
    __shared__ __align__(16) unsigned short zcH[32][40], zcL[32][40]; // [s][k<32]
    __shared__ __align__(16) unsigned short g3H[32][40];              // -softmax fp16
    __shared__ __align__(16) unsigned short h1H[32][232];             // h1 / dh2
    __shared__ __align__(16) unsigned short h2H[32][232];             // h2 / dh1
    __shared__ __align__(16) unsigned short d1H[32][232];             // gelu'(u1); F: gzP alias
    __shared__ __align__(16) unsigned short d2H[32][232];             // gelu'(u2)
    __shared__ float logitsP[2][20][36];
    __shared__ float zF[32][17];
    __shared__ float b1L[208], b2L[208], b3L[20];

    float (*gzP)[16][36] = (float (*)[16][36])&d1H[0][0];  // 9216B <= 14848B

    const int tid = threadIdx.x;
    const int gbase = blockIdx.x * 32;
    const int s16 = tid >> 4, i16 = tid & 15;
    const int w = tid >> 6, lane = tid & 63;
    const int lr = lane & 15, lg = lane >> 4, lg8 = lg * 8;
    const int mt = w & 1, ng = (w >> 1) & 3;
    const int mrow = mt * 16 + lr;

    const f16x8* W1T = (const f16x8*)w1tp;
    const f16x8* W2T = (const f16x8*)w2tp;
    const f16x8* W2D = (const f16x8*)w2dp;
    const f16x8* W3T = (const f16x8*)w3tp;
    const f16x8* W3D = (const f16x8*)w3dp;
    const f16x8* W1D = (const f16x8*)w1dp;

    // zero h pads once (k-slots 208..231 read as zeros by fragments)
    for (int i = tid; i < 32 * 232; i += 512) {
        int r = i / 232, c = i - r * 232;
        h1H[r][c] = 0; h2H[r][c] = 0;
    }
    if (tid < 208) {
        b1L[tid] = (tid < 200) ? b1[tid] : 0.f;
        b2L[tid] = (tid < 200) ? b2[tid] : 0.f;
    }
    if (tid < 20) b3L[tid] = b3[tid];
    {
        float zv = z0[(size_t)(gbase + s16) * 16 + i16];
        zF[s16][i16] = zv;
        unsigned short zh = f2h(zv);
        zcH[s16][i16] = zh;
        zcL[s16][i16] = f2h(zv - h2f(zh));
        float cv = ftraj[(size_t)(gbase + s16) * 16 + i16];
        unsigned short ch = f2h(cv);
        zcH[s16][16 + i16] = ch;
        zcL[s16][16 + i16] = f2h(cv - h2f(ch));
    }
    __syncthreads();

    float eps = noise[(size_t)(gbase + s16) * 16 + i16];

    for (int st = 0; st < 20; ++st) {
        float eps_next = (st < 19)
            ? noise[((size_t)(st + 1) * NTOT + gbase + s16) * 16 + i16] : 0.f;

        // ---- A: u1 = [z|c] @ w1 + b1, N=208, K=32 (input hi/lo, 2 MFMA) ----
        {
            f16x8 Bh = *(const f16x8*)&zcH[mrow][lg8];
            f16x8 Bl = *(const f16x8*)&zcL[mrow][lg8];
            for (int nt = ng; nt < 13; nt += 4) {
                f32x4 acc = {0.f, 0.f, 0.f, 0.f};
                f16x8 af = W1T[nt * 64 + lane];
                acc = __builtin_amdgcn_mfma_f32_16x16x32_f16(af, Bh, acc, 0, 0, 0);
                acc = __builtin_amdgcn_mfma_f32_16x16x32_f16(af, Bl, acc, 0, 0, 0);
                const int n0 = nt * 16 + lg * 4;
                u16x4 hh, dd;
                #pragma unroll
                for (int r = 0; r < 4; ++r) {
                    float hv, dv;
                    gelu_pair_fast(acc[r] + b1L[n0 + r], hv, dv);
                    hh[r] = f2h(hv); dd[r] = f2h(dv);
                }
                *(u16x4*)&h1H[mrow][n0] = hh;
                *(u16x4*)&d1H[mrow][n0] = dd;
            }
        }
        __syncthreads();

        // ---- B: u2 = h1 @ w2 + b2, N=208, K=224 ----
        {
            f16x8 F[7];
            #pragma unroll
            for (int kx = 0; kx < 7; ++kx)
                F[kx] = *(const f16x8*)&h1H[mrow][kx * 32 + lg8];
            for (int nt = ng; nt < 13; nt += 4) {
                f32x4 acc = {0.f, 0.f, 0.f, 0.f};
                const f16x8* wp = W2T + (size_t)nt * 7 * 64 + lane;
                #pragma unroll
                for (int kx = 0; kx < 7; ++kx)
                    acc = __builtin_amdgcn_mfma_f32_16x16x32_f16(wp[kx * 64], F[kx], acc, 0, 0, 0);
                const int n0 = nt * 16 + lg * 4;
                u16x4 hh, dd;
                #pragma unroll
                for (int r = 0; r < 4; ++r) {
                    float hv, dv;
                    gelu_pair_fast(acc[r] + b2L[n0 + r], hv, dv);
                    hh[r] = f2h(hv); dd[r] = f2h(dv);
                }
                *(u16x4*)&h2H[mrow][n0] = hh;
                *(u16x4*)&d2H[mrow][n0] = dd;
            }
        }
        __syncthreads();

        // ---- C: logits = h2 @ w3, N=32(y<20), K=224, 8 waves split-K x2 ----
        {
            const int mtC = w & 1, ntC = (w >> 1) & 1, kc = w >> 2;
            const int mrowC = mtC * 16 + lr;
            const int kxa = kc ? 4 : 0, kxb = kc ? 7 : 4;
            f32x4 acc = {0.f, 0.f, 0.f, 0.f};
            for (int kx = kxa; kx < kxb; ++kx) {
                f16x8 F = *(const f16x8*)&h2H[mrowC][kx * 32 + lg8];
                acc = __builtin_amdgcn_mfma_f32_16x16x32_f16(W3T[(ntC * 7 + kx) * 64 + lane], F, acc, 0, 0, 0);
            }
            const int n0 = ntC * 16 + lg * 4;
            #pragma unroll
            for (int r = 0; r < 4; ++r) {
                int y = n0 + r;
                if (y < 20) logitsP[kc][y][mrowC] = acc[r];
            }
        }
        __syncthreads();

        // ---- softmax: g3 = -softmax(logits) (fp16) ----
        if (tid < 32) {
            const int s = tid;
            float l[20];
            float m = -1e30f;
            #pragma unroll
            for (int y = 0; y < 20; ++y) {
                float v = b3L[y] + logitsP[0][y][s] + logitsP[1][y][s];
                l[y] = v;
                m = fmaxf(m, v);
            }
            float sum = 0.f;
            #pragma unroll
            for (int y = 0; y < 20; ++y) { l[y] = __expf(l[y] - m); sum += l[y]; }
            float inv = -1.0f / sum;
            #pragma unroll
            for (int y = 0; y < 32; ++y)
                g3H[s][y] = f2h((y < 20) ? l[y] * inv : 0.f);
        }
        __syncthreads();

        // ---- D: dh2 = (g3 @ w3^T) * d2, N=208, K=32 -> h1H ----
        {
            f16x8 B = *(const f16x8*)&g3H[mrow][lg8];
            for (int nt = ng; nt < 13; nt += 4) {
                f32x4 acc = {0.f, 0.f, 0.f, 0.f};
                acc = __builtin_amdgcn_mfma_f32_16x16x32_f16(W3D[nt * 64 + lane], B, acc, 0, 0, 0);
                const int n0 = nt * 16 + lg * 4;
                u16x4 dd = *(const u16x4*)&d2H[mrow][n0];
                u16x4 rr;
                #pragma unroll
                for (int r = 0; r < 4; ++r)
                    rr[r] = f2h(acc[r] * h2f(dd[r]));
                *(u16x4*)&h1H[mrow][n0] = rr;
            }
        }
        __syncthreads();

        // ---- E: dh1 = (dh2 @ w2^T) * d1, N=208, K=224 -> h2H ----
        {
            f16x8 F[7];
            #pragma unroll
            for (int kx = 0; kx < 7; ++kx)
                F[kx] = *(const f16x8*)&h1H[mrow][kx * 32 + lg8];
            for (int nt = ng; nt < 13; nt += 4) {
                f32x4 acc = {0.f, 0.f, 0.f, 0.f};
                const f16x8* wp = W2D + (size_t)nt * 7 * 64 + lane;
                #pragma unroll
                for (int kx = 0; kx < 7; ++kx)
                    acc = __builtin_amdgcn_mfma_f32_16x16x32_f16(wp[kx * 64], F[kx], acc, 0, 0, 0);
                const int n0 = nt * 16 + lg * 4;
                u16x4 dd = *(const u16x4*)&d1H[mrow][n0];
                u16x4 rr;
                #pragma unroll
                for (int r = 0; r < 4; ++r)
                    rr[r] = f2h(acc[r] * h2f(dd[r]));
                *(u16x4*)&h2H[mrow][n0] = rr;
            }
        }
        __syncthreads();

        // ---- F: gz = dh1 @ w1[:16]^T, N=16, K=224, split-K x4 (gzP aliases d1H) ----
        {
            const int mtF = w & 1, kc = w >> 1;
            const int mrowF = mtF * 16 + lr;
            const int kxa = kc * 2;
            const int kxb = (kxa + 2 < 7) ? kxa + 2 : 7;
            f32x4 acc = {0.f, 0.f, 0.f, 0.f};
            for (int kx = kxa; kx < kxb; ++kx) {
                f16x8 F = *(const f16x8*)&h2H[mrowF][kx * 32 + lg8];
                acc = __builtin_amdgcn_mfma_f32_16x16x32_f16(W1D[kx * 64 + lane], F, acc, 0, 0, 0);
            }
            #pragma unroll
            for (int r = 0; r < 4; ++r)
                gzP[kc][lg * 4 + r][mrowF] = acc[r];
        }
        __syncthreads();

        // ---- update z (fp32 state; refresh hi/lo fp16 input) ----
        {
            float g = gzP[0][i16][s16] + gzP[1][i16][s16]
                    + gzP[2][i16][s16] + gzP[3][i16][s16];
            float z = zF[s16][i16];
            float zn = z - 0.08f * (g + 0.25f * z) + 0.4f * eps;
            zF[s16][i16] = zn;
            unsigned short zh = f2h(zn);
            zcH[s16][i16] = zh;
            zcL[s16][i16] = f2h(zn - h2f(zh));
            eps = eps_next;
        }
        __syncthreads();
    }

    zout[(size_t)(gbase + s16) * 16 + i16] = zF[s16][i16];
}

// ---------------- Decoder: bf16 MFMA, 16 samples/wg, 512 threads, ~61KB LDS -------
__global__ __launch_bounds__(512) void decoder_kernel(
    const float* __restrict__ ftraj, const float* __restrict__ zfin,
    const unsigned short* __restrict__ wT1, const unsigned short* __restrict__ wT2,
    const unsigned short* __restrict__ wT3, const unsigned short* __restrict__ wT4,
    const float* __restrict__ b1, const float* __restrict__ b2,
    const float* __restrict__ b3, const float* __restrict__ b4,
    float* __restrict__ out)
{
    __shared__ __align__(16) unsigned short xh[16][40];
    __shared__ __align__(16) unsigned short xl[16][40];
    __shared__ __align__(16) unsigned short hA[16][1032];   // h1 then h3
    __shared__ __align__(16) unsigned short hB[16][520];    // h2; then f32 L4 scratch
    __shared__ float b1L[1024], b2L[512], b3L[1024];

    const int tid = threadIdx.x;
    const int gbase = blockIdx.x * 16;
    const int wv = tid >> 6, l = tid & 63;
    const int lr = l & 15, lg = l >> 4;

    for (int i = tid; i < 1024; i += 512) { b1L[i] = b1[i]; b3L[i] = b3[i]; }
    if (tid < 512) b2L[tid] = b2[tid];
    if (tid < 256) {
        int s = tid >> 4, c = tid & 15;
        float vf = ftraj[(size_t)(gbase + s) * 16 + c];
        unsigned short fh = f2bf(vf);
        xh[s][c] = fh;
        xl[s][c] = f2bf(vf - bf2f(fh));
        float vz = zfin[(size_t)(gbase + s) * 16 + c];
        unsigned short zh = f2bf(vz);
        xh[s][16 + c] = zh;
        xl[s][16 + c] = f2bf(vz - bf2f(zh));
    }
    __syncthreads();

    // L1: 32 -> 1024, hi/lo split input. m = lr (16 samples).
    {
        bf16x8 xhf = *(const bf16x8*)&xh[lr][lg * 8];
        bf16x8 xlf = *(const bf16x8*)&xl[lr][lg * 8];
        #pragma unroll 2
        for (int a = 0; a < 8; ++a) {
            const int nt = wv * 8 + a;
            bf16x8 af = *(const bf16x8*)&wT1[(size_t)(nt * 16 + lr) * 40 + lg * 8];
            f32x4 acc = {0.f, 0.f, 0.f, 0.f};
            acc = __builtin_amdgcn_mfma_f32_16x16x32_bf16(af, xhf, acc, 0, 0, 0);
            acc = __builtin_amdgcn_mfma_f32_16x16x32_bf16(af, xlf, acc, 0, 0, 0);
            const int n0 = nt * 16 + lg * 4;
            u16x4 o;
            #pragma unroll
            for (int r = 0; r < 4; ++r)
                o[r] = f2bf(fmaxf(acc[r] + b1L[n0 + r], 0.f));
            *(u16x4*)&hA[lr][n0] = o;
        }
    }
    __syncthreads();

    // L2: 1024 -> 512
    {
        f32x4 acc[4];
        #pragma unroll
        for (int a = 0; a < 4; ++a) acc[a] = (f32x4){0.f, 0.f, 0.f, 0.f};
        #pragma unroll 2
        for (int ks = 0; ks < 32; ++ks) {
            const int k0 = ks * 32;
            bf16x8 bfr = *(const bf16x8*)&hA[lr][k0 + lg * 8];
            #pragma unroll
            for (int a = 0; a < 4; ++a) {
                const int n = (wv * 4 + a) * 16 + lr;
                bf16x8 af = *(const bf16x8*)&wT2[(size_t)n * 1032 + k0 + lg * 8];
                acc[a] = __builtin_amdgcn_mfma_f32_16x16x32_bf16(af, bfr, acc[a], 0, 0, 0);
            }
        }
        #pragma unroll
        for (int a = 0; a < 4; ++a) {
            const int n0 = (wv * 4 + a) * 16 + lg * 4;
            u16x4 o;
            #pragma unroll
            for (int r = 0; r < 4; ++r)
                o[r] = f2bf(fmaxf(acc[a][r] + b2L[n0 + r], 0.f));
            *(u16x4*)&hB[lr][n0] = o;
        }
    }
    __syncthreads();

    // L3: 512 -> 1024
    {
        f32x4 acc[8];
        #pragma unroll
        for (int a = 0; a < 8; ++a) acc[a] = (f32x4){0.f, 0.f, 0.f, 0.f};
        #pragma unroll 1
        for (int ks = 0; ks < 16; ++ks) {
            const int k0 = ks * 32;
            bf16x8 bfr = *(const bf16x8*)&hB[lr][k0 + lg * 8];
            #pragma unroll
            for (int a = 0; a < 8; ++a) {
                const int n = (wv * 8 + a) * 16 + lr;
                bf16x8 af = *(const bf16x8*)&wT3[(size_t)n * 520 + k0 + lg * 8];
                acc[a] = __builtin_amdgcn_mfma_f32_16x16x32_bf16(af, bfr, acc[a], 0, 0, 0);
            }
        }
        __syncthreads();    // hB reads done before L4 scratch overwrite
        #pragma unroll
        for (int a = 0; a < 8; ++a) {
            const int n0 = (wv * 8 + a) * 16 + lg * 4;
            u16x4 o;
            #pragma unroll
            for (int r = 0; r < 4; ++r)
                o[r] = f2bf(fmaxf(acc[a][r] + b3L[n0 + r], 0.f));
            *(u16x4*)&hA[lr][n0] = o;
        }
    }
    __syncthreads();

    // L4: 1024 -> 10(pad 16), split-K over 8 waves. scratch aliases hB (8KB<16.6KB).
    float* pf = (float*)hB;
    {
        f32x4 acc = {0.f, 0.f, 0.f, 0.f};
        #pragma unroll
        for (int q = 0; q < 4; ++q) {
            const int k0 = (wv * 4 + q) * 32;
            bf16x8 af = *(const bf16x8*)&wT4[(size_t)lr * 1032 + k0 + lg * 8];
            bf16x8 bfr = *(const bf16x8*)&hA[lr][k0 + lg * 8];
            acc = __builtin_amdgcn_mfma_f32_16x16x32_bf16(af, bfr, acc, 0, 0, 0);
        }
        *(f32x4*)&pf[(wv * 64 + l) * 4] = acc;
    }
    __syncthreads();
    if (tid < 256) {
        const int m = tid & 15, n = tid >> 4;          // n 0..15
        const int lsrc = ((n >> 2) << 4) | m;
        const int r = n & 3;
        float v = 0.f;
        #pragma unroll
        for (int ww = 0; ww < 8; ++ww)
            v += pf[(ww * 64 + lsrc) * 4 + r];
        if (n < 10)
            out[(size_t)(gbase + m) * 10 + n] = v + b4[n];
    }
}

extern "C" void kernel_launch(void* const* d_in, const int* in_sizes, int n_in,
                              void* d_out, int out_size, void* d_ws, size_t ws_size,
                              hipStream_t stream)
{
    const float* ftraj = (const float*)d_in[0];
    const float* z0    = (const float*)d_in[1];
    const float* noise = (const float*)d_in[2];
    const float* ew1 = (const float*)d_in[3];
    const float* eb1 = (const float*)d_in[4];
    const float* ew2 = (const float*)d_in[5];
    const float* eb2 = (const float*)d_in[6];
    const float* ew3 = (const float*)d_in[7];
    const float* eb3 = (const float*)d_in[8];
    const float* dw1 = (const float*)d_in[9];
    const float* db1 = (const float*)d_in[10];
    const float* dw2 = (const float*)d_in[11];
    const float* db2 = (const float*)d_in[12];
    const float* dw3 = (const float*)d_in[13];
    const float* db3 = (const float*)d_in[14];
    const float* dw4 = (const float*)d_in[15];
    const float* db4 = (const float*)d_in[16];
    float* out = (float*)d_out;

    char* ws = (char*)d_ws;
    float* zfin           = (float*)ws;                           // 4 MB
    unsigned short* w1tp  = (unsigned short*)(ws + 4194304);      // 13312 B
    unsigned short* w2tp  = (unsigned short*)(ws + 4210688);      // 93184 B
    unsigned short* w2dp  = (unsigned short*)(ws + 4308992);      // 93184 B
    unsigned short* w3tp  = (unsigned short*)(ws + 4407296);      // 14336 B
    unsigned short* w3dp  = (unsigned short*)(ws + 4423680);      // 13312 B
    unsigned short* w1dp  = (unsigned short*)(ws + 4440064);      // 7168 B
    unsigned short* wsT1  = (unsigned short*)(ws + 4448256);      // 81920 B
    unsigned short* wsT2  = (unsigned short*)(ws + 4530176);      // 1056768 B
    unsigned short* wsT3  = (unsigned short*)(ws + 5586944);      // 1064960 B
    unsigned short* wsT4  = (unsigned short*)(ws + 6651904);      // 33024 B

    // One fused prep launch: 10 weight transforms + ftraj passthrough copy.
    fused_prep_kernel<<<(SZ_ALL + 511) / 512, 512, 0, stream>>>(
        ew1, ew2, ew3, dw1, dw2, dw3, dw4,
        w1tp, w2tp, w2dp, w3tp, w3dp, w1dp,
        wsT1, wsT2, wsT3, wsT4,
        (const float4*)ftraj, (float4*)(out + (size_t)NTOT * 10));

    langevin_kernel<<<NTOT / 32, 512, 0, stream>>>(
        ftraj, z0, noise,
        w1tp, w2tp, w2dp, w3tp, w3dp, w1dp,
        eb1, eb2, eb3, zfin);
    decoder_kernel<<<NTOT / 16, 512, 0, stream>>>(ftraj, zfin,
                                                  wsT1, wsT2, wsT3, wsT4,
                                                  db1, db2, db3, db4, out);
}

// Round 18
// 1230.992 us; speedup vs baseline: 1.2777x; 1.2777x over previous
//
#include <hip/hip_runtime.h>
#include <hip/hip_bf16.h>

// LBEBM R18 = R16 verbatim (best measured: 1.234ms). Langevin R11-structure
// (0.96ms, 56 VGPR, no spill), decoder R4 32-sample tile (bandwidth-optimal),
// single fused prep launch. R17's 16-sample decoder halved arithmetic
// intensity on the weight stream and regressed; reverted.

#define NTOT 65536

typedef __attribute__((ext_vector_type(8))) _Float16 f16x8;
typedef __attribute__((ext_vector_type(8))) short bf16x8;
typedef __attribute__((ext_vector_type(4))) float f32x4;
typedef __attribute__((ext_vector_type(4))) unsigned short u16x4;

__device__ __forceinline__ unsigned short f2bf(float f) {
    union { float f; unsigned int u; } v; v.f = f;
    unsigned int r = v.u + 0x7fffu + ((v.u >> 16) & 1u);
    return (unsigned short)(r >> 16);
}
__device__ __forceinline__ float bf2f(unsigned short h) {
    union { unsigned int u; float f; } v; v.u = ((unsigned int)h) << 16;
    return v.f;
}
__device__ __forceinline__ unsigned short f2h(float f) {
    union { _Float16 h; unsigned short u; } v; v.h = (_Float16)f; return v.u;
}
__device__ __forceinline__ float h2f(unsigned short u) {
    union { unsigned short u; _Float16 h; } v; v.u = u; return (float)v.h;
}
// gelu val+grad, fast erf (A&S 7.1.26, |err|<=1.5e-7, shares exp(-x^2/2))
__device__ __forceinline__ void gelu_pair_fast(float x, float& val, float& grad) {
    float e = __expf(-0.5f * x * x);
    float pdf = 0.3989422804014326779f * e;
    float y = fabsf(x) * 0.70710678118654752440f;
    float t = __builtin_amdgcn_rcpf(fmaf(0.3275911f, y, 1.0f));
    float poly = t * (0.254829592f + t * (-0.284496736f + t * (1.421413741f
               + t * (-1.453152027f + t * 1.061405429f))));
    float erfv = copysignf(fmaf(-poly, e, 1.0f), x);
    float cdf = fmaf(0.5f, erfv, 0.5f);
    val = x * cdf;
    grad = fmaf(x, pdf, cdf);
}

// ---- fused weight prep: one launch, 10 segments ----
__device__ __forceinline__ void pack_w_elem(const float* src, unsigned short* dst,
                                            int srcR, int srcC, int transposed,
                                            int KT, int idx) {
    int e = idx & 7, lane = (idx >> 3) & 63, t = idx >> 9;
    int kt = t % KT, nt = t / KT;
    int n = nt * 16 + (lane & 15);
    int k = kt * 32 + (lane >> 4) * 8 + e;
    float v = 0.f;
    if (transposed) { if (k < srcR && n < srcC) v = src[(size_t)k * srcC + n]; }
    else            { if (n < srcR && k < srcC) v = src[(size_t)n * srcC + k]; }
    dst[idx] = f2h(v);
}
__device__ __forceinline__ void prep_wT_elem(const float* src, unsigned short* dst,
                                             int K, int Kp, int Nsrc, int idx) {
    int n = idx / Kp, k = idx - n * Kp;
    float v = (k < K && n < Nsrc) ? src[(size_t)k * Nsrc + n] : 0.f;
    dst[idx] = f2bf(v);
}

#define SZ_W1T  6656      // 13*1*512
#define SZ_W2T  46592     // 13*7*512
#define SZ_W2D  46592
#define SZ_W3T  7168      // 2*7*512
#define SZ_W3D  6656
#define SZ_W1D  3584      // 1*7*512
#define SZ_T1   40960     // 1024*40
#define SZ_T2   528384    // 512*1032
#define SZ_T3   532480    // 1024*520
#define SZ_T4   16512     // 16*1032
#define SZ_ALL  (SZ_W1T+SZ_W2T+SZ_W2D+SZ_W3T+SZ_W3D+SZ_W1D+SZ_T1+SZ_T2+SZ_T3+SZ_T4)

__global__ void fused_prep_kernel(
    const float* __restrict__ ew1, const float* __restrict__ ew2,
    const float* __restrict__ ew3,
    const float* __restrict__ dw1, const float* __restrict__ dw2,
    const float* __restrict__ dw3, const float* __restrict__ dw4,
    unsigned short* __restrict__ w1tp, unsigned short* __restrict__ w2tp,
    unsigned short* __restrict__ w2dp, unsigned short* __restrict__ w3tp,
    unsigned short* __restrict__ w3dp, unsigned short* __restrict__ w1dp,
    unsigned short* __restrict__ wsT1, unsigned short* __restrict__ wsT2,
    unsigned short* __restrict__ wsT3, unsigned short* __restrict__ wsT4)
{
    int idx = blockIdx.x * blockDim.x + threadIdx.x;
    if (idx < SZ_W1T) { pack_w_elem(ew1, w1tp, 32, 200, 1, 1, idx); return; }
    idx -= SZ_W1T;
    if (idx < SZ_W2T) { pack_w_elem(ew2, w2tp, 200, 200, 1, 7, idx); return; }
    idx -= SZ_W2T;
    if (idx < SZ_W2D) { pack_w_elem(ew2, w2dp, 200, 200, 0, 7, idx); return; }
    idx -= SZ_W2D;
    if (idx < SZ_W3T) { pack_w_elem(ew3, w3tp, 200, 20, 1, 7, idx); return; }
    idx -= SZ_W3T;
    if (idx < SZ_W3D) { pack_w_elem(ew3, w3dp, 200, 20, 0, 1, idx); return; }
    idx -= SZ_W3D;
    if (idx < SZ_W1D) { pack_w_elem(ew1, w1dp, 32, 200, 0, 7, idx); return; }
    idx -= SZ_W1D;
    if (idx < SZ_T1) { prep_wT_elem(dw1, wsT1, 32, 40, 1024, idx); return; }
    idx -= SZ_T1;
    if (idx < SZ_T2) { prep_wT_elem(dw2, wsT2, 1024, 1032, 512, idx); return; }
    idx -= SZ_T2;
    if (idx < SZ_T3) { prep_wT_elem(dw3, wsT3, 512, 520, 1024, idx); return; }
    idx -= SZ_T3;
    if (idx < SZ_T4) { prep_wT_elem(dw4, wsT4, 1024, 1032, 10, idx); return; }
}

// ---------------- Langevin: 32 samples/wg, 512 threads, ~75KB LDS, 2 wg/CU --------
__global__ __launch_bounds__(512, 4) void langevin_kernel(
    const float* __restrict__ ftraj, const float* __restrict__ z0,
    const float* __restrict__ noise,
    const unsigned short* __restrict__ w1tp, const unsigned short* __restrict__ w2tp,
    const unsigned short* __restrict__ w2dp, const unsigned short* __restrict__ w3tp,
    const unsigned short* __restrict__ w3dp, const unsigned short* __restrict__ w1dp,
    const float* __restrict__ b1, const float* __restrict__ b2,
    const float* __restrict__ b3, float* __restrict__ zout)
{
    __shared__ __align__(16) unsigned short zcH[32][40], zcL[32][40]; // [s][k<32]
    __shared__ __align__(16) unsigned short g3H[32][40];              // -softmax fp16
    __shared__ __align__(16) unsigned short h1H[32][232];             // h1 / dh2
    __shared__ __align__(16) unsigned short h2H[32][232];             // h2 / dh1
    __shared__ __align__(16) unsigned short d1H[32][232];             // gelu'(u1); F: gzP alias
    __shared__ __align__(16) unsigned short d2H[32][232];             // gelu'(u2)
    __shared__ float logitsP[2][20][36];
    __shared__ float zF[32][17];
    __shared__ float b1L[208], b2L[208], b3L[20];

    float (*gzP)[16][36] = (float (*)[16][36])&d1H[0][0];  // 9216B <= 14848B

    const int tid = threadIdx.x;
    const int gbase = blockIdx.x * 32;
    const int s16 = tid >> 4, i16 = tid & 15;
    const int w = tid >> 6, lane = tid & 63;
    const int lr = lane & 15, lg = lane >> 4, lg8 = lg * 8;
    const int mt = w & 1, ng = (w >> 1) & 3;
    const int mrow = mt * 16 + lr;

    const f16x8* W1T = (const f16x8*)w1tp;
    const f16x8* W2T = (const f16x8*)w2tp;
    const f16x8* W2D = (const f16x8*)w2dp;
    const f16x8* W3T = (const f16x8*)w3tp;
    const f16x8* W3D = (const f16x8*)w3dp;
    const f16x8* W1D = (const f16x8*)w1dp;

    // zero h pads once (k-slots 208..231 read as zeros by fragments)
    for (int i = tid; i < 32 * 232; i += 512) {
        int r = i / 232, c = i - r * 232;
        h1H[r][c] = 0; h2H[r][c] = 0;
    }
    if (tid < 208) {
        b1L[tid] = (tid < 200) ? b1[tid] : 0.f;
        b2L[tid] = (tid < 200) ? b2[tid] : 0.f;
    }
    if (tid < 20) b3L[tid] = b3[tid];
    {
        float zv = z0[(size_t)(gbase + s16) * 16 + i16];
        zF[s16][i16] = zv;
        unsigned short zh = f2h(zv);
        zcH[s16][i16] = zh;
        zcL[s16][i16] = f2h(zv - h2f(zh));
        float cv = ftraj[(size_t)(gbase + s16) * 16 + i16];
        unsigned short ch = f2h(cv);
        zcH[s16][16 + i16] = ch;
        zcL[s16][16 + i16] = f2h(cv - h2f(ch));
    }
    __syncthreads();

    float eps = noise[(size_t)(gbase + s16) * 16 + i16];

    for (int st = 0; st < 20; ++st) {
        float eps_next = (st < 19)
            ? noise[((size_t)(st + 1) * NTOT + gbase + s16) * 16 + i16] : 0.f;

        // ---- A: u1 = [z|c] @ w1 + b1, N=208, K=32 (input hi/lo, 2 MFMA) ----
        {
            f16x8 Bh = *(const f16x8*)&zcH[mrow][lg8];
            f16x8 Bl = *(const f16x8*)&zcL[mrow][lg8];
            for (int nt = ng; nt < 13; nt += 4) {
                f32x4 acc = {0.f, 0.f, 0.f, 0.f};
                f16x8 af = W1T[nt * 64 + lane];
                acc = __builtin_amdgcn_mfma_f32_16x16x32_f16(af, Bh, acc, 0, 0, 0);
                acc = __builtin_amdgcn_mfma_f32_16x16x32_f16(af, Bl, acc, 0, 0, 0);
                const int n0 = nt * 16 + lg * 4;
                u16x4 hh, dd;
                #pragma unroll
                for (int r = 0; r < 4; ++r) {
                    float hv, dv;
                    gelu_pair_fast(acc[r] + b1L[n0 + r], hv, dv);
                    hh[r] = f2h(hv); dd[r] = f2h(dv);
                }
                *(u16x4*)&h1H[mrow][n0] = hh;
                *(u16x4*)&d1H[mrow][n0] = dd;
            }
        }
        __syncthreads();

        // ---- B: u2 = h1 @ w2 + b2, N=208, K=224 ----
        {
            f16x8 F[7];
            #pragma unroll
            for (int kx = 0; kx < 7; ++kx)
                F[kx] = *(const f16x8*)&h1H[mrow][kx * 32 + lg8];
            for (int nt = ng; nt < 13; nt += 4) {
                f32x4 acc = {0.f, 0.f, 0.f, 0.f};
                const f16x8* wp = W2T + (size_t)nt * 7 * 64 + lane;
                #pragma unroll
                for (int kx = 0; kx < 7; ++kx)
                    acc = __builtin_amdgcn_mfma_f32_16x16x32_f16(wp[kx * 64], F[kx], acc, 0, 0, 0);
                const int n0 = nt * 16 + lg * 4;
                u16x4 hh, dd;
                #pragma unroll
                for (int r = 0; r < 4; ++r) {
                    float hv, dv;
                    gelu_pair_fast(acc[r] + b2L[n0 + r], hv, dv);
                    hh[r] = f2h(hv); dd[r] = f2h(dv);
                }
                *(u16x4*)&h2H[mrow][n0] = hh;
                *(u16x4*)&d2H[mrow][n0] = dd;
            }
        }
        __syncthreads();

        // ---- C: logits = h2 @ w3, N=32(y<20), K=224, 8 waves split-K x2 ----
        {
            const int mtC = w & 1, ntC = (w >> 1) & 1, kc = w >> 2;
            const int mrowC = mtC * 16 + lr;
            const int kxa = kc ? 4 : 0, kxb = kc ? 7 : 4;
            f32x4 acc = {0.f, 0.f, 0.f, 0.f};
            for (int kx = kxa; kx < kxb; ++kx) {
                f16x8 F = *(const f16x8*)&h2H[mrowC][kx * 32 + lg8];
                acc = __builtin_amdgcn_mfma_f32_16x16x32_f16(W3T[(ntC * 7 + kx) * 64 + lane], F, acc, 0, 0, 0);
            }
            const int n0 = ntC * 16 + lg * 4;
            #pragma unroll
            for (int r = 0; r < 4; ++r) {
                int y = n0 + r;
                if (y < 20) logitsP[kc][y][mrowC] = acc[r];
            }
        }
        __syncthreads();

        // ---- softmax: g3 = -softmax(logits) (fp16) ----
        if (tid < 32) {
            const int s = tid;
            float l[20];
            float m = -1e30f;
            #pragma unroll
            for (int y = 0; y < 20; ++y) {
                float v = b3L[y] + logitsP[0][y][s] + logitsP[1][y][s];
                l[y] = v;
                m = fmaxf(m, v);
            }
            float sum = 0.f;
            #pragma unroll
            for (int y = 0; y < 20; ++y) { l[y] = __expf(l[y] - m); sum += l[y]; }
            float inv = -1.0f / sum;
            #pragma unroll
            for (int y = 0; y < 32; ++y)
                g3H[s][y] = f2h((y < 20) ? l[y] * inv : 0.f);
        }
        __syncthreads();

        // ---- D: dh2 = (g3 @ w3^T) * d2, N=208, K=32 -> h1H ----
        {
            f16x8 B = *(const f16x8*)&g3H[mrow][lg8];
            for (int nt = ng; nt < 13; nt += 4) {
                f32x4 acc = {0.f, 0.f, 0.f, 0.f};
                acc = __builtin_amdgcn_mfma_f32_16x16x32_f16(W3D[nt * 64 + lane], B, acc, 0, 0, 0);
                const int n0 = nt * 16 + lg * 4;
                u16x4 dd = *(const u16x4*)&d2H[mrow][n0];
                u16x4 rr;
                #pragma unroll
                for (int r = 0; r < 4; ++r)
                    rr[r] = f2h(acc[r] * h2f(dd[r]));
                *(u16x4*)&h1H[mrow][n0] = rr;
            }
        }
        __syncthreads();

        // ---- E: dh1 = (dh2 @ w2^T) * d1, N=208, K=224 -> h2H ----
        {
            f16x8 F[7];
            #pragma unroll
            for (int kx = 0; kx < 7; ++kx)
                F[kx] = *(const f16x8*)&h1H[mrow][kx * 32 + lg8];
            for (int nt = ng; nt < 13; nt += 4) {
                f32x4 acc = {0.f, 0.f, 0.f, 0.f};
                const f16x8* wp = W2D + (size_t)nt * 7 * 64 + lane;
                #pragma unroll
                for (int kx = 0; kx < 7; ++kx)
                    acc = __builtin_amdgcn_mfma_f32_16x16x32_f16(wp[kx * 64], F[kx], acc, 0, 0, 0);
                const int n0 = nt * 16 + lg * 4;
                u16x4 dd = *(const u16x4*)&d1H[mrow][n0];
                u16x4 rr;
                #pragma unroll
                for (int r = 0; r < 4; ++r)
                    rr[r] = f2h(acc[r] * h2f(dd[r]));
                *(u16x4*)&h2H[mrow][n0] = rr;
            }
        }
        __syncthreads();

        // ---- F: gz = dh1 @ w1[:16]^T, N=16, K=224, split-K x4 (gzP aliases d1H) ----
        {
            const int mtF = w & 1, kc = w >> 1;
            const int mrowF = mtF * 16 + lr;
            const int kxa = kc * 2;
            const int kxb = (kxa + 2 < 7) ? kxa + 2 : 7;
            f32x4 acc = {0.f, 0.f, 0.f, 0.f};
            for (int kx = kxa; kx < kxb; ++kx) {
                f16x8 F = *(const f16x8*)&h2H[mrowF][kx * 32 + lg8];
                acc = __builtin_amdgcn_mfma_f32_16x16x32_f16(W1D[kx * 64 + lane], F, acc, 0, 0, 0);
            }
            #pragma unroll
            for (int r = 0; r < 4; ++r)
                gzP[kc][lg * 4 + r][mrowF] = acc[r];
        }
        __syncthreads();

        // ---- update z (fp32 state; refresh hi/lo fp16 input) ----
        {
            float g = gzP[0][i16][s16] + gzP[1][i16][s16]
                    + gzP[2][i16][s16] + gzP[3][i16][s16];
            float z = zF[s16][i16];
            float zn = z - 0.08f * (g + 0.25f * z) + 0.4f * eps;
            zF[s16][i16] = zn;
            unsigned short zh = f2h(zn);
            zcH[s16][i16] = zh;
            zcL[s16][i16] = f2h(zn - h2f(zh));
            eps = eps_next;
        }
        __syncthreads();
    }

    zout[(size_t)(gbase + s16) * 16 + i16] = zF[s16][i16];
}

// ---------------- Decoder: bf16 MFMA, 32 samples/wg, 512 threads (R4) -------------
__global__ __launch_bounds__(512) void decoder_kernel(
    const float* __restrict__ ftraj, const float* __restrict__ zfin,
    const unsigned short* __restrict__ wT1, const unsigned short* __restrict__ wT2,
    const unsigned short* __restrict__ wT3, const unsigned short* __restrict__ wT4,
    const float* __restrict__ b1, const float* __restrict__ b2,
    const float* __restrict__ b3, const float* __restrict__ b4,
    float* __restrict__ out)
{
    __shared__ __align__(16) unsigned short xh[32][40];
    __shared__ __align__(16) unsigned short xl[32][40];
    __shared__ __align__(16) unsigned short hA[32][1032];
    __shared__ __align__(16) unsigned short hB[32][520];
    __shared__ float b1L[1024], b2L[512], b3L[1024];

    const int tid = threadIdx.x;
    const int gbase = blockIdx.x * 32;
    const int wv = tid >> 6, l = tid & 63;
    const int lr = l & 15, lg = l >> 4;

    for (int i = tid; i < 1024; i += 512) { b1L[i] = b1[i]; b3L[i] = b3[i]; }
    if (tid < 512) b2L[tid] = b2[tid];
    {
        int s = tid >> 4, c = tid & 15;
        float vf = ftraj[(size_t)(gbase + s) * 16 + c];
        unsigned short fh = f2bf(vf);
        xh[s][c] = fh;
        xl[s][c] = f2bf(vf - bf2f(fh));
        float vz = zfin[(size_t)(gbase + s) * 16 + c];
        unsigned short zh = f2bf(vz);
        xh[s][16 + c] = zh;
        xl[s][16 + c] = f2bf(vz - bf2f(zh));
    }
    __syncthreads();

    // L1: 32 -> 1024, hi/lo split input
    {
        bf16x8 xhf[2], xlf[2];
        #pragma unroll
        for (int mt = 0; mt < 2; ++mt) {
            xhf[mt] = *(const bf16x8*)&xh[mt * 16 + lr][lg * 8];
            xlf[mt] = *(const bf16x8*)&xl[mt * 16 + lr][lg * 8];
        }
        #pragma unroll 2
        for (int a = 0; a < 8; ++a) {
            const int nt = wv * 8 + a;
            bf16x8 af = *(const bf16x8*)&wT1[(size_t)(nt * 16 + lr) * 40 + lg * 8];
            f32x4 acc0 = {0.f, 0.f, 0.f, 0.f}, acc1 = {0.f, 0.f, 0.f, 0.f};
            acc0 = __builtin_amdgcn_mfma_f32_16x16x32_bf16(af, xhf[0], acc0, 0, 0, 0);
            acc0 = __builtin_amdgcn_mfma_f32_16x16x32_bf16(af, xlf[0], acc0, 0, 0, 0);
            acc1 = __builtin_amdgcn_mfma_f32_16x16x32_bf16(af, xhf[1], acc1, 0, 0, 0);
            acc1 = __builtin_amdgcn_mfma_f32_16x16x32_bf16(af, xlf[1], acc1, 0, 0, 0);
            const int n0 = nt * 16 + lg * 4;
            u16x4 o0, o1;
            #pragma unroll
            for (int r = 0; r < 4; ++r) {
                float bb = b1L[n0 + r];
                o0[r] = f2bf(fmaxf(acc0[r] + bb, 0.f));
                o1[r] = f2bf(fmaxf(acc1[r] + bb, 0.f));
            }
            *(u16x4*)&hA[lr][n0] = o0;
            *(u16x4*)&hA[16 + lr][n0] = o1;
        }
    }
    __syncthreads();

    // L2: 1024 -> 512
    {
        f32x4 acc[4][2];
        #pragma unroll
        for (int a = 0; a < 4; ++a)
            #pragma unroll
            for (int mt = 0; mt < 2; ++mt) acc[a][mt] = (f32x4){0.f, 0.f, 0.f, 0.f};
        #pragma unroll 2
        for (int ks = 0; ks < 32; ++ks) {
            const int k0 = ks * 32;
            bf16x8 bfr[2];
            #pragma unroll
            for (int mt = 0; mt < 2; ++mt)
                bfr[mt] = *(const bf16x8*)&hA[mt * 16 + lr][k0 + lg * 8];
            #pragma unroll
            for (int a = 0; a < 4; ++a) {
                const int n = (wv * 4 + a) * 16 + lr;
                bf16x8 af = *(const bf16x8*)&wT2[(size_t)n * 1032 + k0 + lg * 8];
                acc[a][0] = __builtin_amdgcn_mfma_f32_16x16x32_bf16(af, bfr[0], acc[a][0], 0, 0, 0);
                acc[a][1] = __builtin_amdgcn_mfma_f32_16x16x32_bf16(af, bfr[1], acc[a][1], 0, 0, 0);
            }
        }
        #pragma unroll
        for (int a = 0; a < 4; ++a) {
            const int n0 = (wv * 4 + a) * 16 + lg * 4;
            #pragma unroll
            for (int mt = 0; mt < 2; ++mt) {
                u16x4 o;
                #pragma unroll
                for (int r = 0; r < 4; ++r)
                    o[r] = f2bf(fmaxf(acc[a][mt][r] + b2L[n0 + r], 0.f));
                *(u16x4*)&hB[mt * 16 + lr][n0] = o;
            }
        }
    }
    __syncthreads();

    // L3: 512 -> 1024
    {
        f32x4 acc[8][2];
        #pragma unroll
        for (int a = 0; a < 8; ++a)
            #pragma unroll
            for (int mt = 0; mt < 2; ++mt) acc[a][mt] = (f32x4){0.f, 0.f, 0.f, 0.f};
        #pragma unroll 1
        for (int ks = 0; ks < 16; ++ks) {
            const int k0 = ks * 32;
            bf16x8 bfr[2];
            #pragma unroll
            for (int mt = 0; mt < 2; ++mt)
                bfr[mt] = *(const bf16x8*)&hB[mt * 16 + lr][k0 + lg * 8];
            #pragma unroll
            for (int a = 0; a < 8; ++a) {
                const int n = (wv * 8 + a) * 16 + lr;
                bf16x8 af = *(const bf16x8*)&wT3[(size_t)n * 520 + k0 + lg * 8];
                acc[a][0] = __builtin_amdgcn_mfma_f32_16x16x32_bf16(af, bfr[0], acc[a][0], 0, 0, 0);
                acc[a][1] = __builtin_amdgcn_mfma_f32_16x16x32_bf16(af, bfr[1], acc[a][1], 0, 0, 0);
            }
        }
        #pragma unroll
        for (int a = 0; a < 8; ++a) {
            const int n0 = (wv * 8 + a) * 16 + lg * 4;
            #pragma unroll
            for (int mt = 0; mt < 2; ++mt) {
                u16x4 o;
                #pragma unroll
                for (int r = 0; r < 4; ++r)
                    o[r] = f2bf(fmaxf(acc[a][mt][r] + b3L[n0 + r], 0.f));
                *(u16x4*)&hA[mt * 16 + lr][n0] = o;
            }
        }
    }
    __syncthreads();

    // L4: 1024 -> 10(pad 16), split-K over 8 waves
    float* pf = (float*)hB;
    {
        f32x4 acc[2];
        acc[0] = (f32x4){0.f, 0.f, 0.f, 0.f};
        acc[1] = (f32x4){0.f, 0.f, 0.f, 0.f};
        #pragma unroll
        for (int q = 0; q < 4; ++q) {
            const int k0 = (wv * 4 + q) * 32;
            bf16x8 af = *(const bf16x8*)&wT4[(size_t)lr * 1032 + k0 + lg * 8];
            #pragma unroll
            for (int mt = 0; mt < 2; ++mt) {
                bf16x8 bfr = *(const bf16x8*)&hA[mt * 16 + lr][k0 + lg * 8];
                acc[mt] = __builtin_amdgcn_mfma_f32_16x16x32_bf16(af, bfr, acc[mt], 0, 0, 0);
            }
        }
        #pragma unroll
        for (int mt = 0; mt < 2; ++mt)
            *(f32x4*)&pf[((wv * 2 + mt) * 64 + l) * 4] = acc[mt];
    }
    __syncthreads();
    {
        const int m = tid & 31, n = tid >> 5;
        const int lsrc = ((n >> 2) << 4) | (m & 15);
        const int r = n & 3, mt = m >> 4;
        float v = 0.f;
        #pragma unroll
        for (int ww = 0; ww < 8; ++ww)
            v += pf[((ww * 2 + mt) * 64 + lsrc) * 4 + r];
        if (n < 10)
            out[(size_t)(gbase + m) * 10 + n] = v + b4[n];
    }
}

__global__ void copy_ftraj_kernel(const float4* __restrict__ src, float4* __restrict__ dst) {
    int idx = blockIdx.x * blockDim.x + threadIdx.x;
    dst[idx] = src[idx];
}

extern "C" void kernel_launch(void* const* d_in, const int* in_sizes, int n_in,
                              void* d_out, int out_size, void* d_ws, size_t ws_size,
                              hipStream_t stream)
{
    const float* ftraj = (const float*)d_in[0];
    const float* z0    = (const float*)d_in[1];
    const float* noise = (const float*)d_in[2];
    const float* ew1 = (const float*)d_in[3];
    const float* eb1 = (const float*)d_in[4];
    const float* ew2 = (const float*)d_in[5];
    const float* eb2 = (const float*)d_in[6];
    const float* ew3 = (const float*)d_in[7];
    const float* eb3 = (const float*)d_in[8];
    const float* dw1 = (const float*)d_in[9];
    const float* db1 = (const float*)d_in[10];
    const float* dw2 = (const float*)d_in[11];
    const float* db2 = (const float*)d_in[12];
    const float* dw3 = (const float*)d_in[13];
    const float* db3 = (const float*)d_in[14];
    const float* dw4 = (const float*)d_in[15];
    const float* db4 = (const float*)d_in[16];
    float* out = (float*)d_out;

    char* ws = (char*)d_ws;
    float* zfin           = (float*)ws;                           // 4 MB
    unsigned short* w1tp  = (unsigned short*)(ws + 4194304);      // 13312 B
    unsigned short* w2tp  = (unsigned short*)(ws + 4210688);      // 93184 B
    unsigned short* w2dp  = (unsigned short*)(ws + 4308992);      // 93184 B
    unsigned short* w3tp  = (unsigned short*)(ws + 4407296);      // 14336 B
    unsigned short* w3dp  = (unsigned short*)(ws + 4423680);      // 13312 B
    unsigned short* w1dp  = (unsigned short*)(ws + 4440064);      // 7168 B
    unsigned short* wsT1  = (unsigned short*)(ws + 4448256);      // 81920 B
    unsigned short* wsT2  = (unsigned short*)(ws + 4530176);      // 1056768 B
    unsigned short* wsT3  = (unsigned short*)(ws + 5586944);      // 1064960 B
    unsigned short* wsT4  = (unsigned short*)(ws + 6651904);      // 33024 B

    // One fused prep launch for all 10 weight-transform segments.
    fused_prep_kernel<<<(SZ_ALL + 511) / 512, 512, 0, stream>>>(
        ew1, ew2, ew3, dw1, dw2, dw3, dw4,
        w1tp, w2tp, w2dp, w3tp, w3dp, w1dp,
        wsT1, wsT2, wsT3, wsT4);

    langevin_kernel<<<NTOT / 32, 512, 0, stream>>>(
        ftraj, z0, noise,
        w1tp, w2tp, w2dp, w3tp, w3dp, w1dp,
        eb1, eb2, eb3, zfin);
    decoder_kernel<<<NTOT / 32, 512, 0, stream>>>(ftraj, zfin,
                                                  wsT1, wsT2, wsT3, wsT4,
                                                  db1, db2, db3, db4, out);
    copy_ftraj_kernel<<<512, 512, 0, stream>>>((const float4*)ftraj,
                                               (float4*)(out + (size_t)NTOT * 10));
}